// Round 5
// baseline (288.378 us; speedup 1.0000x reference)
//
#include <hip/hip_runtime.h>
#include <stdint.h>

#define TT 16
#define BB 16
#define CC 256
#define HS 31
#define HT 15
#define OUTW 17
#define NCHAN (BB*TT*CC)            // 65536
#define CORR_ELEMS ((size_t)NCHAN*OUTW*OUTW)
#define SW 48                       // s-row width per copy (f16): reads reach pos 47
#define NW 4                        // waves per block (1 channel per wave)

typedef _Float16 half8 __attribute__((ext_vector_type(8)));
typedef float    f32x4 __attribute__((ext_vector_type(4)));

// logical channel ch = (b*T + t)*C + c  ->  s_f index (t*B + b)*C + c
__device__ __forceinline__ int s_index(int ch) {
    int bt = ch >> 8, c = ch & 255;
    int b = bt >> 4, t = bt & 15;
    return (t * BB + b) * CC + c;
}

__device__ __forceinline__ unsigned packh2(float a, float b) {
    return __builtin_bit_cast(unsigned, __builtin_amdgcn_cvt_pkrtz(a, b));
}

// 16B A-fragment from 4B-aligned LDS (can't use b128: only 4B alignment).
__device__ __forceinline__ half8 ldsA(const _Float16* p) {
    const unsigned* u = (const unsigned*)p;
    union { unsigned x[4]; half8 h; } r;
    r.x[0] = u[0]; r.x[1] = u[1]; r.x[2] = u[2]; r.x[3] = u[3];
    return r.h;
}

__global__ __launch_bounds__(256, 4)
void corr_mfma(const float* __restrict__ s_f, const float* __restrict__ t_f,
               float* __restrict__ corr)
{
    // Per wave: s2 = two 2B-shifted f16 copies of the 31x31 tile (row 31 = 0);
    //           wl = w padded to 16x32 (kx>=15, ky=15 zero); r2 = R[ky][y] f16.
    __shared__ __align__(16) _Float16 s2[NW][2][32][SW];   // 6144 B / wave
    __shared__ __align__(16) _Float16 wl[NW][16][32];      // 1024 B / wave
    __shared__ __align__(16) _Float16 r2[NW][16][32];      // 1024 B / wave

    const int tid  = threadIdx.x;
    const int w    = tid >> 6;
    const int lane = tid & 63;
    const int ch   = blockIdx.x * NW + w;

    // ---- zero s2 + wl (wave-private; in-order LDS, no barrier needed) ----
    {
        uint4 z{0, 0, 0, 0};
        uint4* p = (uint4*)&s2[w][0][0][0];           // 384 x b128
#pragma unroll
        for (int i = 0; i < 6; ++i) p[i * 64 + lane] = z;
        ((uint4*)&wl[w][0][0])[lane] = z;             // 64 x b128
    }

    // ---- stage s: coalesced f32 loads -> f16, two shifted copies ----
    {
        const float* src = s_f + (size_t)s_index(ch) * (HS * HS);
#pragma unroll
        for (int i = 0; i < 16; ++i) {
            int e = i * 64 + lane;
            if (e < HS * HS) {
                int y = e / HS;
                int x = e - y * HS;
                _Float16 v = (_Float16)src[e];
                s2[w][0][y][x] = v;                   // copy0: pos = x
                if (x > 0) s2[w][1][y][x - 1] = v;    // copy1: pos = x-1
            }
        }
    }

    // ---- stage w ----
    {
        const int bt = ch >> 8, c = ch & 255, b = bt >> 4;
        const float* wsrc = t_f + (size_t)(b * CC + c) * (HT * HT);
#pragma unroll
        for (int i = 0; i < 4; ++i) {
            int e = i * 64 + lane;
            if (e < HT * HT) {
                int ky = e / HT;
                int kx = e - ky * HT;
                wl[w][ky][kx] = (_Float16)wsrc[e];
            }
        }
    }

    // ---- B fragment (per-channel constant): lane holds w[ky=lane&15][8*(lane>>4)+j] ----
    const int r = lane & 15;       // A row / B col / C col(=ky)
    const int q = lane >> 4;       // k-group
    half8 bfrag = *(const half8*)&wl[w][r][8 * q];    // 16B-aligned

    // stage-2 lane constants: lane = oy + 17*h, h in 0..2 sums ky = 5h..5h+4
    const int  h   = lane / 17;
    const int  oy  = lane - 17 * h;
    const bool act = (h < 3);
    const _Float16* r2h  = &r2[w][0][0];
    const int       rbase = oy + (5 * h) * 33;        // f16 index; +33 per ky
    float* outp = corr + (size_t)ch * (OUTW * OUTW) + oy * OUTW;

    const f32x4 zero{0.f, 0.f, 0.f, 0.f};

    for (int ox = 0; ox < OUTW; ++ox) {
        const int c  = ox & 1;
        const int pb = (ox - c) + 8 * q;              // even -> 4B-aligned reads

        half8 a0 = ldsA(&s2[w][c][r][pb]);            // rows 0..15
        half8 a1 = ldsA(&s2[w][c][r + 16][pb]);       // rows 16..31

        f32x4 c0 = __builtin_amdgcn_mfma_f32_16x16x32_f16(a0, bfrag, zero, 0, 0, 0);
        f32x4 c1 = __builtin_amdgcn_mfma_f32_16x16x32_f16(a1, bfrag, zero, 0, 0, 0);

        // R[y=4q+reg(+16)][ky=r] -> r2[ky][y] as f16 pairs (8B-aligned b64 writes)
        {
            uint2 v0{packh2(c0[0], c0[1]), packh2(c0[2], c0[3])};
            uint2 v1{packh2(c1[0], c1[1]), packh2(c1[2], c1[3])};
            *(uint2*)&r2[w][r][4 * q]      = v0;
            *(uint2*)&r2[w][r][4 * q + 16] = v1;
        }

        // stage 2: out[oy][ox] = sum_ky r2[ky][oy+ky]  (f16 idx = oy + 33*ky)
        if (act) {
            _Float16 acc = (_Float16)0;
#pragma unroll
            for (int k = 0; k < 5; ++k)
                acc += r2h[rbase + k * 33];
            float p  = (float)acc;
            float p1 = __shfl(p, (lane + 17) & 63);
            float p2 = __shfl(p, (lane + 34) & 63);
            if (h == 0) outp[ox] = p + p1 + p2;
        }
    }
}

__global__ void masks_kernel(const float* __restrict__ corr,
                             const int* __restrict__ pos,
                             float* __restrict__ masks)
{
    int gid = blockIdx.x * 256 + threadIdx.x;   // flattened (b*T+t)*C + c
    if (gid >= NCHAN) return;
    int bt = gid >> 8;
    int b  = bt >> 4;
    int t  = bt & 15;
    int p0 = pos[(b * TT + t) * 2 + 0];
    int p1 = pos[(b * TT + t) * 2 + 1];
    masks[gid] = corr[(size_t)gid * (OUTW * OUTW) + p0 * OUTW + p1];
}

extern "C" void kernel_launch(void* const* d_in, const int* in_sizes, int n_in,
                              void* d_out, int out_size, void* d_ws, size_t ws_size,
                              hipStream_t stream)
{
    const float* s_f = (const float*)d_in[0];
    const float* t_f = (const float*)d_in[1];
    const int*   pos = (const int*)d_in[2];
    float* corr  = (float*)d_out;
    float* masks = corr + CORR_ELEMS;

    corr_mfma<<<NCHAN / NW, 256, 0, stream>>>(s_f, t_f, corr);
    masks_kernel<<<NCHAN / 256, 256, 0, stream>>>(corr, pos, masks);
}

// Round 6
// 167.813 us; speedup vs baseline: 1.7185x; 1.7185x over previous
//
#include <hip/hip_runtime.h>
#include <stdint.h>

#define TT 16
#define BB 16
#define CC 256
#define HS 31
#define HT 15
#define OUTW 17
#define NCH 14                      // channels (flattened b,t,c) per block
#define NCHAN (BB*TT*CC)            // 65536
#define CORR_ELEMS ((size_t)NCHAN*OUTW*OUTW)
#define SROW 17                     // dwords per s row (16 data + 1 pad)
#define SCH  545                    // dwords per s channel; 545 % 32 == 1 -> bank = 17*tid + c
#define WCH  120                    // dwords per w channel (15 rows * 8)

typedef _Float16 h2_t __attribute__((ext_vector_type(2)));

__device__ __forceinline__ unsigned packh2(float a, float b) {
    return __builtin_bit_cast(unsigned, __builtin_amdgcn_cvt_pkrtz(a, b));
}
__device__ __forceinline__ float fdot2f(unsigned a, unsigned b, float c) {
    return __builtin_amdgcn_fdot2(__builtin_bit_cast(h2_t, a),
                                  __builtin_bit_cast(h2_t, b), c, false);
}

// logical channel ch = (b*T + t)*C + c  ->  s_f index (t*B + b)*C + c
__device__ __forceinline__ int s_index(int ch) {
    int bt = ch >> 8, c = ch & 255;
    int b = bt >> 4, t = bt & 15;
    return (t * BB + b) * CC + c;
}

__global__ __launch_bounds__(256, 4)
void corr_kernel(const float* __restrict__ s_f, const float* __restrict__ t_f,
                 float* __restrict__ corr)
{
    __shared__ unsigned s_lds[NCH * SCH];   // 30520 B
    __shared__ unsigned w_lds[NCH * WCH];   //  6720 B

    const int tid = threadIdx.x;
    const int ch_base = blockIdx.x * NCH;

    // ---- stage s: f32 pairs -> packed f16; row y at dword 17*y (linear, no swizzle) ----
    {
        const int jcol = tid & 15;          // u32 col 0..15 (covers f16 2j, 2j+1)
        const int r0   = tid >> 4;          // row 0..15
        const int x0   = 2 * jcol;
        const bool hasb  = (jcol < 15);     // x=31 doesn't exist -> pad 0
        const int  r1    = r0 + 16;
        const bool hasr1 = (r1 <= 30);
#pragma unroll
        for (int j = 0; j < NCH; ++j) {
            int ch = ch_base + j; if (ch >= NCHAN) ch = NCHAN - 1;
            const float* src = s_f + (size_t)s_index(ch) * (HS * HS);
            float a0 = src[r0 * HS + x0];
            float b0 = hasb ? src[r0 * HS + x0 + 1] : 0.0f;
            s_lds[j * SCH + r0 * SROW + jcol] = packh2(a0, b0);
            if (hasr1) {
                float a1 = src[r1 * HS + x0];
                float b1 = hasb ? src[r1 * HS + x0 + 1] : 0.0f;
                s_lds[j * SCH + r1 * SROW + jcol] = packh2(a1, b1);
            }
        }
    }

    // ---- stage w: 15 f16 per row packed into 8 u32 (last pair hi = 0) ----
    for (int idx = tid; idx < NCH * HT * 8; idx += 256) {
        int j   = idx / (HT * 8);
        int rem = idx - j * (HT * 8);
        int ky  = rem >> 3;
        int p   = rem & 7;
        int ch  = ch_base + j; if (ch >= NCHAN) ch = NCHAN - 1;
        int bt = ch >> 8, c = ch & 255, b = bt >> 4;
        const float* wsrc = t_f + (size_t)(b * CC + c) * (HT * HT) + ky * HT;
        float a  = wsrc[2 * p];
        float bb = (p < 7) ? wsrc[2 * p + 1] : 0.0f;
        w_lds[j * WCH + ky * 8 + p] = packh2(a, bb);
    }

    __syncthreads();

    // ---- compute: thread = (c_sub, oy) owns one 17-wide output row ----
    const int c_sub = tid / OUTW;
    const int oy    = tid - c_sub * OUTW;
    if (c_sub >= NCH) return;
    const int ch = ch_base + c_sub;
    if (ch >= NCHAN) return;

    const unsigned* sbase = &s_lds[c_sub * SCH + oy * SROW];
    const unsigned* wbase = &w_lds[c_sub * WCH];

    float acc[OUTW];
#pragma unroll
    for (int m = 0; m < OUTW; ++m) acc[m] = 0.0f;

#pragma unroll
    for (int ky = 0; ky < HT; ++ky) {
        // s row (y = oy+ky): 16 u32, immediate offsets; bank = 17*tid + const -> 2-way (free)
        unsigned sp[16];
#pragma unroll
        for (int u = 0; u < 16; ++u) sp[u] = sbase[ky * SROW + u];

        // w row: 8 packed pairs (broadcast within c_sub group)
        uint4 w0 = *(const uint4*)(wbase + ky * 8);
        uint4 w1 = *(const uint4*)(wbase + ky * 8 + 4);
        unsigned wp[8] = {w0.x, w0.y, w0.z, w0.w, w1.x, w1.y, w1.z, w1.w};
        // wo[r] = (w[2r-1], w[2r]), w[-1] = 0
        unsigned wo[8];
        wo[0] = wp[0] << 16;
#pragma unroll
        for (int r = 1; r < 8; ++r)
            wo[r] = __builtin_amdgcn_alignbit(wp[r], wp[r - 1], 16);

        // even output cols m = 2e
#pragma unroll
        for (int e = 0; e < 9; ++e)
#pragma unroll
            for (int jj = 0; jj < 8; ++jj)
                acc[2 * e] = fdot2f(sp[e + jj], wp[jj], acc[2 * e]);
        // odd output cols m = 2o+1
#pragma unroll
        for (int o = 0; o < 8; ++o)
#pragma unroll
            for (int r = 0; r < 8; ++r)
                acc[2 * o + 1] = fdot2f(sp[o + r], wo[r], acc[2 * o + 1]);
    }

    size_t base = (size_t)ch * (OUTW * OUTW) + (size_t)oy * OUTW;
#pragma unroll
    for (int m = 0; m < OUTW; ++m) corr[base + m] = acc[m];
}

__global__ void masks_kernel(const float* __restrict__ corr,
                             const int* __restrict__ pos,
                             float* __restrict__ masks)
{
    int gid = blockIdx.x * 256 + threadIdx.x;   // flattened (b*T+t)*C + c
    if (gid >= NCHAN) return;
    int bt = gid >> 8;
    int b  = bt >> 4;
    int t  = bt & 15;
    int p0 = pos[(b * TT + t) * 2 + 0];
    int p1 = pos[(b * TT + t) * 2 + 1];
    masks[gid] = corr[(size_t)gid * (OUTW * OUTW) + p0 * OUTW + p1];
}

extern "C" void kernel_launch(void* const* d_in, const int* in_sizes, int n_in,
                              void* d_out, int out_size, void* d_ws, size_t ws_size,
                              hipStream_t stream)
{
    const float* s_f = (const float*)d_in[0];
    const float* t_f = (const float*)d_in[1];
    const int*   pos = (const int*)d_in[2];
    float* corr  = (float*)d_out;
    float* masks = corr + CORR_ELEMS;

    int nblocks = (NCHAN + NCH - 1) / NCH;   // 4682
    corr_kernel<<<nblocks, 256, 0, stream>>>(s_f, t_f, corr);
    masks_kernel<<<NCHAN / 256, 256, 0, stream>>>(corr, pos, masks);
}